// Round 11
// baseline (309.140 us; speedup 1.0000x reference)
//
#include <hip/hip_runtime.h>
#include <hip/hip_cooperative_groups.h>

namespace cg = cooperative_groups;

// Ragged gather-to-padded for SparseConvUnet preprocessing.
// feature: [Nrows, 128] f32 packed; atom_num: [N] int32 in [0,14);
// out = concat( padded [N,14,128] f32 (zero where slot>=atom_num), label as f32 [N] ).
//
// R11: single cooperative kernel (512x1024, exactly resident at 2 blocks/CU).
// Phase 1: per-block local scan of a contiguous residue chunk (+label cast).
// Phase 2: add global base from the 512 chunk totals.   (grid.sync between)
// Phase 3: identical R6 gather loop (stride-interleaved tiles, nt+nt,
// per-lane masks). Eliminates 2 launches + 2 full-pipeline drains.
// Assumes n <= GBLOCKS*GTHREADS (rpb <= 1024); n=100000 -> rpb=196.

#define MAX_ATOMS 14
#define F4_PER_ROW 32                       // 128 floats = 32 float4
#define F4_PER_RES (MAX_ATOMS * F4_PER_ROW) // 448 = 7 * 64
#define TILE 16                             // residues per block-iteration (= waves/block)
#define GBLOCKS 512
#define GTHREADS 1024

typedef float f32x4 __attribute__((ext_vector_type(4)));

__global__ __launch_bounds__(GTHREADS, 8) void k_fused(
        const f32x4* __restrict__ feat,
        const int* __restrict__ atom_num,
        const int* __restrict__ label,
        f32x4* __restrict__ out,
        float* __restrict__ out_label,
        int* __restrict__ ws_off,          // [n] per-residue offsets
        int* __restrict__ ws_sums,         // [GBLOCKS] chunk totals
        int n, int ntiles, int rpb) {
    cg::grid_group grid = cg::this_grid();
    __shared__ int scn[GTHREADS];
    int t = threadIdx.x;
    int b = blockIdx.x;

    // ---- phase 1: local exclusive scan of this block's contiguous chunk ----
    int r = b * rpb + t;
    int v = (t < rpb && r < n) ? atom_num[r] : 0;
    scn[t] = v;
    __syncthreads();
    for (int d = 1; d < GTHREADS; d <<= 1) {
        int add = (t >= d) ? scn[t - d] : 0;
        __syncthreads();
        scn[t] += add;
        __syncthreads();
    }
    if (t < rpb && r < n) {
        ws_off[r] = scn[t] - v;            // local exclusive prefix
        out_label[r] = (float)label[r];    // harness reads d_out as f32
    }
    if (t == GTHREADS - 1) ws_sums[b] = scn[t];
    grid.sync();

    // ---- phase 2: add global base (sum of preceding chunk totals) ----
    scn[t] = (t < b) ? ws_sums[t] : 0;     // b < GBLOCKS <= GTHREADS
    __syncthreads();
    for (int d = GTHREADS / 2; d > 0; d >>= 1) {
        if (t < d) scn[t] += scn[t + d];
        __syncthreads();
    }
    int base = scn[0];
    if (t < rpb && r < n) ws_off[r] += base;
    grid.sync();

    // ---- phase 3: R6 gather (unchanged) ----
    int w       = t >> 6;                  // wave 0..15
    int lane    = t & 63;
    int halfrow = lane >> 5;               // which row of the lane's pair

    for (int tile = b; tile < ntiles; tile += GBLOCKS) {
        int rr = tile * TILE + w;          // one residue per wave
        if (rr < n) {
            int off = ws_off[rr];          // wave-uniform broadcast load (L2-hot)
            int cnt = atom_num[rr];
            const f32x4* fp = feat + (size_t)off * F4_PER_ROW + lane;
            f32x4* op = out + (size_t)rr * F4_PER_RES + lane;
            #pragma unroll
            for (int i = 0; i < 7; ++i) {
                f32x4 vv = (f32x4)0.f;
                if (2 * i + halfrow < cnt)
                    vv = __builtin_nontemporal_load(fp + i * 64);
                __builtin_nontemporal_store(vv, op + i * 64);
            }
        }
    }
}

extern "C" void kernel_launch(void* const* d_in, const int* in_sizes, int n_in,
                              void* d_out, int out_size, void* d_ws, size_t ws_size,
                              hipStream_t stream) {
    const f32x4* feature = (const f32x4*)d_in[0];
    const int* atom_num  = (const int*)d_in[1];
    const int* label     = (const int*)d_in[2];
    int n = in_sizes[1];                     // N_res = 100000

    f32x4* out = (f32x4*)d_out;
    float* out_label = (float*)d_out + (size_t)n * MAX_ATOMS * 128;

    int* ws_off  = (int*)d_ws;               // n ints
    int* ws_sums = ws_off + n;               // GBLOCKS ints

    int ntiles = (n + TILE - 1) / TILE;      // 6250
    int rpb = (n + GBLOCKS - 1) / GBLOCKS;   // 196 (must be <= GTHREADS)

    void* args[] = { (void*)&feature, (void*)&atom_num, (void*)&label,
                     (void*)&out, (void*)&out_label,
                     (void*)&ws_off, (void*)&ws_sums,
                     (void*)&n, (void*)&ntiles, (void*)&rpb };
    hipLaunchCooperativeKernel((const void*)k_fused,
                               dim3(GBLOCKS), dim3(GTHREADS),
                               args, 0, stream);
}

// Round 12
// 223.534 us; speedup vs baseline: 1.3830x; 1.3830x over previous
//
#include <hip/hip_runtime.h>

// Ragged gather-to-padded for SparseConvUnet preprocessing.
// feature: [Nrows, 128] f32 packed; atom_num: [N] int32 in [0,14);
// out = concat( padded [N,14,128] f32 (zero where slot>=atom_num), label as f32 [N] ).
//
// R12: R6 gather (unchanged, best at 206.9us) + single fused prep kernel:
// block b computes its global base by directly summing atom_num[0..b*256)
// (coalesced, L2-hot, no inter-kernel dependency), then scans its chunk.
// 3 launches -> 2; one fewer full-pipeline drain.

#define MAX_ATOMS 14
#define F4_PER_ROW 32                       // 128 floats = 32 float4
#define F4_PER_RES (MAX_ATOMS * F4_PER_ROW) // 448 = 7 * 64
#define TILE 16                             // residues per block-iteration (= waves/block)
#define GBLOCKS 512
#define GTHREADS 1024

typedef float f32x4 __attribute__((ext_vector_type(4)));

// ---- fused prep: offsets + label cast, no dependency on another kernel ----
__global__ __launch_bounds__(256) void k_prep(const int* __restrict__ atom_num,
                                              const int* __restrict__ label,
                                              int n,
                                              int* __restrict__ offsets,
                                              float* __restrict__ out_label) {
    __shared__ int red[256];
    __shared__ int scn[256];
    int t = threadIdx.x;
    int b = blockIdx.x;
    int chunk0 = b << 8;

    // base = sum atom_num[0 .. chunk0): coalesced strided reads, L2-hot
    int part = 0;
    for (int j = t; j < chunk0; j += 256) part += atom_num[j];
    red[t] = part;
    __syncthreads();
    for (int d = 128; d > 0; d >>= 1) {
        if (t < d) red[t] += red[t + d];
        __syncthreads();
    }
    int base = red[0];

    // exclusive scan of this chunk
    int r = chunk0 + t;
    int v = (r < n) ? atom_num[r] : 0;
    scn[t] = v;
    __syncthreads();
    for (int d = 1; d < 256; d <<= 1) {
        int add = (t >= d) ? scn[t - d] : 0;
        __syncthreads();
        scn[t] += add;
        __syncthreads();
    }
    if (r < n) {
        offsets[r] = base + scn[t] - v;
        out_label[r] = (float)label[r];     // harness reads d_out as f32
    }
}

// ---- streaming gather: R6, byte-for-byte ----
__global__ __launch_bounds__(GTHREADS, 8) void k_gather(
        const f32x4* __restrict__ feat,
        const int* __restrict__ atom_num,
        const int* __restrict__ offsets,
        f32x4* __restrict__ out,
        int n, int ntiles) {
    int w       = threadIdx.x >> 6;        // wave 0..15
    int lane    = threadIdx.x & 63;
    int halfrow = lane >> 5;               // which row of the lane's pair

    for (int tile = blockIdx.x; tile < ntiles; tile += GBLOCKS) {
        int r = tile * TILE + w;           // one residue per wave
        if (r < n) {
            int off = offsets[r];          // wave-uniform broadcast load (L2-hot)
            int cnt = atom_num[r];
            const f32x4* fp = feat + (size_t)off * F4_PER_ROW + lane;
            f32x4* op = out + (size_t)r * F4_PER_RES + lane;
            #pragma unroll
            for (int i = 0; i < 7; ++i) {
                f32x4 v = (f32x4)0.f;
                if (2 * i + halfrow < cnt)
                    v = __builtin_nontemporal_load(fp + i * 64);
                __builtin_nontemporal_store(v, op + i * 64);
            }
        }
    }
}

extern "C" void kernel_launch(void* const* d_in, const int* in_sizes, int n_in,
                              void* d_out, int out_size, void* d_ws, size_t ws_size,
                              hipStream_t stream) {
    const float* feature = (const float*)d_in[0];
    const int* atom_num  = (const int*)d_in[1];
    const int* label     = (const int*)d_in[2];
    const int n = in_sizes[1];               // N_res = 100000

    float* out = (float*)d_out;
    float* out_label = out + (size_t)n * MAX_ATOMS * 128;

    int* ws_offsets = (int*)d_ws;            // n ints

    int nb = (n + 255) / 256;                // 391
    k_prep<<<nb, 256, 0, stream>>>(atom_num, label, n, ws_offsets, out_label);

    int ntiles = (n + TILE - 1) / TILE;      // 6250
    k_gather<<<GBLOCKS, GTHREADS, 0, stream>>>(
        (const f32x4*)feature, atom_num, ws_offsets,
        (f32x4*)out, n, ntiles);
}

// Round 13
// 206.751 us; speedup vs baseline: 1.4952x; 1.0812x over previous
//
#include <hip/hip_runtime.h>

// Ragged gather-to-padded for SparseConvUnet preprocessing.
// feature: [Nrows, 128] f32 packed; atom_num: [N] int32 in [0,14);
// out = concat( padded [N,14,128] f32 (zero where slot>=atom_num), label as f32 [N] ).
//
// R13 = R6 restored (best measured config, 206.9us):
//  - k_sums + k_prep (391 blocks each): per-256-chunk totals, then per-residue
//    offsets from L2-hot chunk sums + label cast.
//  - k_gather: 512x1024 (exactly resident, 2 blocks/CU), stride-interleaved
//    16-residue tiles (compact ~58MB rolling front, 512 lockstep streams),
//    nt loads + nt stores, per-lane-masked loads (scheduler-friendly).
// Axes closed: issue shape, cache hints, concurrency, partition, burst
// shape, launch fusion — all locally optimal here.

#define MAX_ATOMS 14
#define F4_PER_ROW 32                       // 128 floats = 32 float4
#define F4_PER_RES (MAX_ATOMS * F4_PER_ROW) // 448 = 7 * 64
#define TILE 16                             // residues per block-iteration (= waves/block)
#define GBLOCKS 512
#define GTHREADS 1024

typedef float f32x4 __attribute__((ext_vector_type(4)));

// ---- kernel A: per-256-residue chunk sums ----
__global__ __launch_bounds__(256) void k_sums(const int* __restrict__ atom_num,
                                              int n, int* __restrict__ sums) {
    __shared__ int lds[256];
    int t = threadIdx.x;
    int r = blockIdx.x * 256 + t;
    lds[t] = (r < n) ? atom_num[r] : 0;
    __syncthreads();
    for (int d = 128; d > 0; d >>= 1) {
        if (t < d) lds[t] += lds[t + d];
        __syncthreads();
    }
    if (t == 0) sums[blockIdx.x] = lds[0];
}

// ---- kernel B: per-residue offsets + label cast ----
__global__ __launch_bounds__(256) void k_prep(const int* __restrict__ atom_num,
                                              const int* __restrict__ sums,
                                              const int* __restrict__ label,
                                              int n,
                                              int* __restrict__ offsets,
                                              float* __restrict__ out_label) {
    __shared__ int red[256];
    __shared__ int scn[256];
    int t = threadIdx.x;
    int b = blockIdx.x;
    int part = 0;
    for (int j = t; j < b; j += 256) part += sums[j];
    red[t] = part;
    __syncthreads();
    for (int d = 128; d > 0; d >>= 1) {
        if (t < d) red[t] += red[t + d];
        __syncthreads();
    }
    int base = red[0];
    int r = b * 256 + t;
    int v = (r < n) ? atom_num[r] : 0;
    scn[t] = v;
    __syncthreads();
    for (int d = 1; d < 256; d <<= 1) {
        int add = (t >= d) ? scn[t - d] : 0;
        __syncthreads();
        scn[t] += add;
        __syncthreads();
    }
    if (r < n) {
        offsets[r] = base + scn[t] - v;
        out_label[r] = (float)label[r];     // harness reads d_out as f32
    }
}

// ---- kernel C: pure streaming gather, fully resident, lockstep front ----
__global__ __launch_bounds__(GTHREADS, 8) void k_gather(
        const f32x4* __restrict__ feat,
        const int* __restrict__ atom_num,
        const int* __restrict__ offsets,
        f32x4* __restrict__ out,
        int n, int ntiles) {
    int w       = threadIdx.x >> 6;        // wave 0..15
    int lane    = threadIdx.x & 63;
    int halfrow = lane >> 5;               // which row of the lane's pair

    for (int tile = blockIdx.x; tile < ntiles; tile += GBLOCKS) {
        int r = tile * TILE + w;           // one residue per wave
        if (r < n) {
            int off = offsets[r];          // wave-uniform broadcast load (L2-hot)
            int cnt = atom_num[r];
            const f32x4* fp = feat + (size_t)off * F4_PER_ROW + lane;
            f32x4* op = out + (size_t)r * F4_PER_RES + lane;
            #pragma unroll
            for (int i = 0; i < 7; ++i) {
                f32x4 v = (f32x4)0.f;
                if (2 * i + halfrow < cnt)
                    v = __builtin_nontemporal_load(fp + i * 64);
                __builtin_nontemporal_store(v, op + i * 64);
            }
        }
    }
}

extern "C" void kernel_launch(void* const* d_in, const int* in_sizes, int n_in,
                              void* d_out, int out_size, void* d_ws, size_t ws_size,
                              hipStream_t stream) {
    const float* feature = (const float*)d_in[0];
    const int* atom_num  = (const int*)d_in[1];
    const int* label     = (const int*)d_in[2];
    const int n = in_sizes[1];               // N_res = 100000

    float* out = (float*)d_out;
    float* out_label = out + (size_t)n * MAX_ATOMS * 128;

    int nb = (n + 255) / 256;                // 391
    int* ws_sums    = (int*)d_ws;            // nb ints
    int* ws_offsets = ws_sums + nb;          // n ints

    k_sums<<<nb, 256, 0, stream>>>(atom_num, n, ws_sums);
    k_prep<<<nb, 256, 0, stream>>>(atom_num, ws_sums, label, n,
                                   ws_offsets, out_label);

    int ntiles = (n + TILE - 1) / TILE;      // 6250
    k_gather<<<GBLOCKS, GTHREADS, 0, stream>>>(
        (const f32x4*)feature, atom_num, ws_offsets,
        (f32x4*)out, n, ntiles);
}